// Round 1
// baseline (56.975 us; speedup 1.0000x reference)
//
#include <hip/hip_runtime.h>

#define G 64
#define NN 64
#define TT 4096
#define EDGES 131072
#define FF 128

#define OUT_ETOT 0
#define OUT_NODEE 64
#define OUT_Q (64 + 4096)
#define OUT_NF (64 + 4096 + 4096)

__device__ __forceinline__ float wave_sum_f(float v) {
#pragma unroll
    for (int m = 1; m < 64; m <<= 1) v += __shfl_xor(v, m);
    return v;
}
__device__ __forceinline__ double wave_sum_d(double v) {
#pragma unroll
    for (int m = 1; m < 64; m <<= 1) v += __shfl_xor(v, m);
    return v;
}

// ---------------- edge scatter: last-write-wins via atomicMax on edge index ----
__global__ void k_scatter(const int* __restrict__ ei, int* __restrict__ winner) {
    int e = blockIdx.x * blockDim.x + threadIdx.x;
    if (e >= EDGES) return;
    int i = ei[e];
    int j = ei[EDGES + e];
    // edges are always intra-graph; cell = i*64 + (j % 64)
    atomicMax(&winner[(i << 6) + (j & 63)], e);
}

// ---------------- per-graph kernel: matrices, E2b, triangular solve, matvecs ---
__global__ __launch_bounds__(256) void k_graph(
    const float* __restrict__ node_attrs, const float* __restrict__ edge_len,
    const float* __restrict__ kappa, const float* __restrict__ ref_eta,
    const float* __restrict__ ref_log_sigma, const float* __restrict__ ref_A,
    const float* __restrict__ ref_B, const float* __restrict__ ref_C,
    const float* __restrict__ ref_D, const float* __restrict__ ref_mu,
    const int* __restrict__ winner,
    float* __restrict__ P_in, float* __restrict__ W_in, float* __restrict__ aE2b,
    float* __restrict__ qc, float* __restrict__ coef, float* __restrict__ qsum) {
    __shared__ float s_factor[64][65];
    __shared__ float s_fcf[64][65];
    __shared__ float s_q[64];
    __shared__ int s_type[64];
    __shared__ float s_gam[4][4];
    __shared__ float s_diag[64];
    __shared__ float s_sigma[4];
    __shared__ float s_A[16], s_B[16], s_C[16], s_D[16], s_mu[16];

    const int g = blockIdx.x;
    const int tid = threadIdx.x;
    const int lane = tid & 63;
    const int wv = tid >> 6;
    const float SQRT_PI = 1.7724538509055159f;
    const float SQRT2 = 1.41421356237309515f;
    const float th1 = tanhf(1.0f);
    const float c1 = th1 * th1 * th1;

    if (tid < 4) s_sigma[tid] = expf(ref_log_sigma[tid]);
    if (tid < 16) {
        s_A[tid] = ref_A[tid]; s_B[tid] = ref_B[tid]; s_C[tid] = ref_C[tid];
        s_D[tid] = ref_D[tid]; s_mu[tid] = ref_mu[tid];
    }
    if (tid < 64) {
        const float* row = node_attrs + (size_t)(g * 64 + tid) * 4;
        int t = 0;
        float best = row[0];
#pragma unroll
        for (int k = 1; k < 4; ++k) {
            float v = row[k];
            if (v > best) { best = v; t = k; }
        }
        s_type[tid] = t;
        float sg = expf(ref_log_sigma[t]);
        s_diag[tid] = ref_eta[t] + 1.0f / (sg * SQRT_PI);
        coef[g * 64 + tid] = 0.5f / (sg * SQRT_PI);
    }
    __syncthreads();
    if (tid < 16) {
        int a = tid >> 2, b = tid & 3;
        s_gam[a][b] = sqrtf(s_sigma[a] * s_sigma[a] + s_sigma[b] * s_sigma[b]);
    }
    __syncthreads();

    // ---- phase 1: build factor / factor*Fc matrices; E2b row sums ----
#pragma unroll 1
    for (int r = 0; r < 16; ++r) {
        int li = r * 4 + wv;
        int lj = lane;
        int wdx = winner[((g * 64 + li) << 6) + lj];
        float R = (wdx >= 0) ? edge_len[wdx] : 0.5f;
        int ti = s_type[li], tj = s_type[lj];
        float gam = s_gam[ti][tj];
        float factor = erff(R / (SQRT2 * gam)) / R;
        float fc;
        if (R < 1.0f) fc = c1;
        else if (R <= 6.0f) {
            float t = tanhf(1.0f - (R - 1.0f) / 5.0f);
            fc = t * t * t;
        } else fc = 0.0f;
        s_factor[li][lj] = factor;
        s_fcf[li][lj] = factor * fc;
        float e2b = 0.0f;
        if (li != lj) {
            int tt = ti * 4 + tj;
            float R2 = R * R;
            float R6 = R2 * R2 * R2;
            e2b = (s_A[tt] * expf(s_B[tt] * (s_mu[tt] - R)) - s_C[tt] / R6 -
                   s_D[tt] / (R6 * R2)) * fc;
        }
        e2b = wave_sum_f(e2b);
        if (lane == 0) aE2b[g * 64 + li] = 0.5f * e2b;
    }
    __syncthreads();

    // ---- phase 2: dual forward substitution (fp64), one wave ----
    if (tid < 64) {
        const int i = tid;
        double Ld = (double)(s_diag[i] + s_factor[i][i]);
        double au = 1.0;
        double av = (double)kappa[g * 64 + i];
        double my_u = 0.0, my_v = 0.0;
        for (int j = 0; j < 64; ++j) {
            double uj = __shfl(au, j);
            double vj = __shfl(av, j);
            double dj = __shfl(Ld, j);
            uj /= dj; vj /= dj;
            if (i == j) { my_u = uj; my_v = vj; }
            if (i > j) {
                double Lij = (double)s_factor[i][j];
                au -= Lij * uj;
                av -= Lij * vj;
            }
        }
        double Su = wave_sum_d(my_u);
        double Sv = wave_sum_d(my_v);
        double lam = Sv / Su;  // q = -v + (Sv/Su)*u  (ensures sum(q)=0)
        float q = (float)(-my_v + lam * my_u);
        s_q[i] = q;
        qc[g * 64 + i] = q;
        float sq = wave_sum_f(q);
        if (i == 0) qsum[g] = sq;
    }
    __syncthreads();

    // ---- phase 3: within-block matvec row sums ----
#pragma unroll 1
    for (int r = 0; r < 16; ++r) {
        int li = r * 4 + wv;
        int lj = lane;
        float q = s_q[lj];
        float p = s_fcf[li][lj] * q;
        float w = s_factor[li][lj] * q;
        p = wave_sum_f(p);
        w = wave_sum_f(w);
        if (lane == 0) {
            P_in[g * 64 + li] = p;
            W_in[g * 64 + li] = w;
        }
    }
}

// ---------------- total charge ------------------------------------------------
__global__ void k_qall(const float* __restrict__ qsum, float* __restrict__ Qall) {
    float v = qsum[threadIdx.x];
    v = wave_sum_f(v);
    if (threadIdx.x == 0) Qall[0] = v;
}

// ---------------- per-node epilogue ------------------------------------------
__global__ __launch_bounds__(256) void k_node(
    const float* __restrict__ P_in, const float* __restrict__ W_in,
    const float* __restrict__ aE2b, const float* __restrict__ qc,
    const float* __restrict__ coef, const float* __restrict__ qsum,
    const float* __restrict__ Qall, const float* __restrict__ atomic_short,
    float* __restrict__ aEel_ws, float* __restrict__ out) {
    int i = blockIdx.x * blockDim.x + threadIdx.x;
    if (i >= TT) return;
    int g = i >> 6;
    const float th1 = tanhf(1.0f);
    const float c1 = th1 * th1 * th1;
    const float factor_off = erff(0.5f / (1.41421356237309515f * 0.5f)) / 0.5f;
    float off = Qall[0] - qsum[g];
    float q = qc[i];
    float ap = P_in[i] + factor_off * c1 * off;
    float V = W_in[i] + factor_off * off + coef[i] * q;
    float aEel = q * V;
    aEel_ws[i] = aEel;
    out[OUT_NODEE + i] = aEel + aE2b[i] + atomic_short[i];
    out[OUT_Q + i] = q;
    float* nf = out + OUT_NF + (size_t)i * 130;
    nf[128] = q;
    nf[129] = ap;
}

// ---------------- node_feats copy (float2, stride-130 rows) -------------------
__global__ __launch_bounds__(256) void k_feats(const float* __restrict__ nf_in,
                                               float* __restrict__ out) {
    int idx = blockIdx.x * blockDim.x + threadIdx.x;  // TT*64 float2 units
    if (idx >= TT * 64) return;
    int i = idx >> 6;
    int k = idx & 63;
    float2 v = ((const float2*)nf_in)[idx];
    *(float2*)(out + OUT_NF + (size_t)i * 130 + k * 2) = v;
}

// ---------------- per-graph energy total --------------------------------------
__global__ void k_etot(const float* __restrict__ aEel,
                       const float* __restrict__ aE2b,
                       const float* __restrict__ short_e,
                       float* __restrict__ out) {
    int g = blockIdx.x;
    int lane = threadIdx.x;
    float v = aEel[g * 64 + lane] + aE2b[g * 64 + lane];
    v = wave_sum_f(v);
    if (lane == 0) out[OUT_ETOT + g] = v + short_e[g];
}

extern "C" void kernel_launch(void* const* d_in, const int* in_sizes, int n_in,
                              void* d_out, int out_size, void* d_ws, size_t ws_size,
                              hipStream_t stream) {
    const float* node_attrs = (const float*)d_in[1];
    const int* edge_index = (const int*)d_in[2];
    const float* edge_length = (const float*)d_in[3];
    const float* kappa = (const float*)d_in[4];
    const float* node_feats = (const float*)d_in[5];
    const float* ref_eta = (const float*)d_in[6];
    const float* ref_log_sigma = (const float*)d_in[7];
    const float* ref_A = (const float*)d_in[8];
    const float* ref_B = (const float*)d_in[9];
    const float* ref_C = (const float*)d_in[10];
    const float* ref_D = (const float*)d_in[11];
    const float* ref_mu = (const float*)d_in[12];
    const float* short_energy = (const float*)d_in[13];
    const float* atomic_short = (const float*)d_in[14];

    float* out = (float*)d_out;
    char* ws = (char*)d_ws;
    int* winner = (int*)ws;                       // TT*64 ints = 1 MiB
    float* P_in = (float*)(ws + (1 << 20));
    float* W_in = P_in + TT;
    float* aE2b = W_in + TT;
    float* qc = aE2b + TT;
    float* coef = qc + TT;
    float* aEel = coef + TT;
    float* qsum = aEel + TT;
    float* Qall = qsum + G;

    hipMemsetAsync(winner, 0xFF, (size_t)TT * 64 * sizeof(int), stream);
    k_scatter<<<EDGES / 256, 256, 0, stream>>>(edge_index, winner);
    k_graph<<<G, 256, 0, stream>>>(node_attrs, edge_length, kappa, ref_eta,
                                   ref_log_sigma, ref_A, ref_B, ref_C, ref_D,
                                   ref_mu, winner, P_in, W_in, aE2b, qc, coef,
                                   qsum);
    k_qall<<<1, 64, 0, stream>>>(qsum, Qall);
    k_node<<<TT / 256, 256, 0, stream>>>(P_in, W_in, aE2b, qc, coef, qsum, Qall,
                                         atomic_short, aEel, out);
    k_feats<<<(TT * 64) / 256, 256, 0, stream>>>(node_feats, out);
    k_etot<<<G, 64, 0, stream>>>(aEel, aE2b, short_energy, out);
}

// Round 2
// 42.025 us; speedup vs baseline: 1.3557x; 1.3557x over previous
//
#include <hip/hip_runtime.h>

#define G 64
#define NN 64
#define TT 4096
#define EDGES 131072
#define FF 128

#define OUT_ETOT 0
#define OUT_NODEE 64
#define OUT_Q (64 + 4096)
#define OUT_NF (64 + 4096 + 4096)

__device__ __forceinline__ float wave_sum_f(float v) {
#pragma unroll
    for (int m = 1; m < 64; m <<= 1) v += __shfl_xor(v, m);
    return v;
}
__device__ __forceinline__ double wave_sum_d(double v) {
#pragma unroll
    for (int m = 1; m < 64; m <<= 1) v += __shfl_xor(v, m);
    return v;
}

// ---------------- edge scatter: last-write-wins via atomicMax on edge index ----
__global__ void k_scatter(const int* __restrict__ ei, int* __restrict__ winner) {
    int e = blockIdx.x * blockDim.x + threadIdx.x;
    if (e >= EDGES) return;
    int i = ei[e];
    int j = ei[EDGES + e];
    atomicMax(&winner[(i << 6) + (j & 63)], e);
}

// ---------------- per-graph kernel: matrices, E2b, triangular solve, matvecs ---
__global__ __launch_bounds__(256) void k_graph(
    const float* __restrict__ node_attrs, const float* __restrict__ edge_len,
    const float* __restrict__ kappa, const float* __restrict__ ref_eta,
    const float* __restrict__ ref_log_sigma, const float* __restrict__ ref_A,
    const float* __restrict__ ref_B, const float* __restrict__ ref_C,
    const float* __restrict__ ref_D, const float* __restrict__ ref_mu,
    const int* __restrict__ winner,
    float* __restrict__ P_in, float* __restrict__ W_in, float* __restrict__ aE2b,
    float* __restrict__ qc, float* __restrict__ coef, float* __restrict__ qsum) {
    __shared__ float s_factor[64][65];
    __shared__ float s_fcf[64][65];
    __shared__ float s_q[64];
    __shared__ int s_type[64];
    __shared__ float s_gam[4][4];
    __shared__ float s_diag[64];
    __shared__ float s_sigma[4];
    __shared__ float s_A[16], s_B[16], s_C[16], s_D[16], s_mu[16];

    const int g = blockIdx.x;
    const int tid = threadIdx.x;
    const int lane = tid & 63;
    const int wv = tid >> 6;
    const float SQRT_PI = 1.7724538509055159f;
    const float SQRT2 = 1.41421356237309515f;
    const float th1 = tanhf(1.0f);
    const float c1 = th1 * th1 * th1;

    // ---- batch ALL global loads for phase 1 up-front (32 independent loads) --
    int widx[16];
#pragma unroll
    for (int r = 0; r < 16; ++r) {
        int li = (r << 2) + wv;
        widx[r] = winner[(((g << 6) + li) << 6) + lane];
    }
    float Rv[16];
#pragma unroll
    for (int r = 0; r < 16; ++r) {
        Rv[r] = (widx[r] >= 0) ? edge_len[widx[r]] : 0.5f;
    }

    if (tid < 4) s_sigma[tid] = __expf(ref_log_sigma[tid]);
    if (tid < 16) {
        s_A[tid] = ref_A[tid]; s_B[tid] = ref_B[tid]; s_C[tid] = ref_C[tid];
        s_D[tid] = ref_D[tid]; s_mu[tid] = ref_mu[tid];
    }
    if (tid < 64) {
        const float* row = node_attrs + (size_t)(g * 64 + tid) * 4;
        int t = 0;
        float best = row[0];
#pragma unroll
        for (int k = 1; k < 4; ++k) {
            float v = row[k];
            if (v > best) { best = v; t = k; }
        }
        s_type[tid] = t;
        float sg = __expf(ref_log_sigma[t]);
        s_diag[tid] = ref_eta[t] + 1.0f / (sg * SQRT_PI);
        coef[g * 64 + tid] = 0.5f / (sg * SQRT_PI);
    }
    __syncthreads();
    if (tid < 16) {
        int a = tid >> 2, b = tid & 3;
        s_gam[a][b] = sqrtf(s_sigma[a] * s_sigma[a] + s_sigma[b] * s_sigma[b]);
    }
    __syncthreads();

    // ---- phase 1: build factor / factor*Fc matrices; E2b row sums (unrolled) -
    const int tj = s_type[lane];
    float e2b[16];
#pragma unroll
    for (int r = 0; r < 16; ++r) {
        int li = (r << 2) + wv;
        float R = Rv[r];
        int ti = s_type[li];
        float gam = s_gam[ti][tj];
        float factor = erff(R / (SQRT2 * gam)) / R;
        float fc;
        if (R < 1.0f) fc = c1;
        else if (R <= 6.0f) {
            float x = 1.0f - (R - 1.0f) * 0.2f;      // in [0,1]
            float ex = __expf(2.0f * x);
            float t = (ex - 1.0f) / (ex + 1.0f);     // tanh(x)
            fc = t * t * t;
        } else fc = 0.0f;
        s_factor[li][lane] = factor;
        s_fcf[li][lane] = factor * fc;
        float e = 0.0f;
        if (li != lane) {
            int t4 = ti * 4 + tj;
            float R2 = R * R;
            float R6 = R2 * R2 * R2;
            e = (s_A[t4] * __expf(s_B[t4] * (s_mu[t4] - R)) - s_C[t4] / R6 -
                 s_D[t4] / (R6 * R2)) * fc;
        }
        e2b[r] = e;
    }
    // 16 independent butterfly chains, interleaved for ILP
#pragma unroll
    for (int m = 1; m < 64; m <<= 1) {
#pragma unroll
        for (int r = 0; r < 16; ++r) e2b[r] += __shfl_xor(e2b[r], m);
    }
    if (lane == 0) {
#pragma unroll
        for (int r = 0; r < 16; ++r)
            aE2b[(g << 6) + (r << 2) + wv] = 0.5f * e2b[r];
    }
    __syncthreads();

    // ---- phase 2: dual forward substitution (fp64), one wave, divides hoisted
    if (tid < 64) {
        const int i = tid;
        double Ld = (double)(s_diag[i] + s_factor[i][i]);
        double inv = 1.0 / Ld;
        double au = 1.0;
        double av = (double)kappa[g * 64 + i];
        double my_u = 0.0, my_v = 0.0;
        for (int j = 0; j < 64; ++j) {
            double ij = __shfl(inv, j);
            double uj = __shfl(au, j) * ij;
            double vj = __shfl(av, j) * ij;
            if (i == j) { my_u = uj; my_v = vj; }
            if (i > j) {
                double Lij = (double)s_factor[i][j];
                au -= Lij * uj;
                av -= Lij * vj;
            }
        }
        double Su = wave_sum_d(my_u);
        double Sv = wave_sum_d(my_v);
        double lam = Sv / Su;  // q = -v + (Sv/Su)*u  (ensures sum(q)=0)
        float q = (float)(-my_v + lam * my_u);
        s_q[i] = q;
        qc[g * 64 + i] = q;
        float sq = wave_sum_f(q);
        if (i == 0) qsum[g] = sq;
    }
    __syncthreads();

    // ---- phase 3: within-block matvec row sums (unrolled, interleaved) -------
    const float qlane = s_q[lane];
    float p[16], w[16];
#pragma unroll
    for (int r = 0; r < 16; ++r) {
        int li = (r << 2) + wv;
        p[r] = s_fcf[li][lane] * qlane;
        w[r] = s_factor[li][lane] * qlane;
    }
#pragma unroll
    for (int m = 1; m < 64; m <<= 1) {
#pragma unroll
        for (int r = 0; r < 16; ++r) {
            p[r] += __shfl_xor(p[r], m);
            w[r] += __shfl_xor(w[r], m);
        }
    }
    if (lane == 0) {
#pragma unroll
        for (int r = 0; r < 16; ++r) {
            P_in[(g << 6) + (r << 2) + wv] = p[r];
            W_in[(g << 6) + (r << 2) + wv] = w[r];
        }
    }
}

// ---------------- per-node epilogue (fused Qall + E_tot reduction) ------------
__global__ __launch_bounds__(256) void k_node(
    const float* __restrict__ P_in, const float* __restrict__ W_in,
    const float* __restrict__ aE2b, const float* __restrict__ qc,
    const float* __restrict__ coef, const float* __restrict__ qsum,
    const float* __restrict__ atomic_short, const float* __restrict__ short_e,
    float* __restrict__ out) {
    int i = blockIdx.x * blockDim.x + threadIdx.x;  // node id; wave == graph
    int lane = threadIdx.x & 63;
    int g = i >> 6;
    const float th1 = tanhf(1.0f);
    const float c1 = th1 * th1 * th1;
    const float factor_off = erff(0.5f / (1.41421356237309515f * 0.5f)) / 0.5f;

    float Qall = wave_sum_f(qsum[lane]);
    float off = Qall - qsum[g];
    float q = qc[i];
    float ap = P_in[i] + factor_off * c1 * off;
    float V = W_in[i] + factor_off * off + coef[i] * q;
    float aEel = q * V;
    float e2 = aE2b[i];
    out[OUT_NODEE + i] = aEel + e2 + atomic_short[i];
    out[OUT_Q + i] = q;
    float* nf = out + OUT_NF + (size_t)i * 130;
    nf[128] = q;
    nf[129] = ap;
    float etot = wave_sum_f(aEel + e2);
    if (lane == 0) out[OUT_ETOT + g] = etot + short_e[g];
}

// ---------------- node_feats copy (float2, stride-130 rows) -------------------
__global__ __launch_bounds__(256) void k_feats(const float* __restrict__ nf_in,
                                               float* __restrict__ out) {
    int idx = blockIdx.x * blockDim.x + threadIdx.x;  // TT*64 float2 units
    if (idx >= TT * 64) return;
    int i = idx >> 6;
    int k = idx & 63;
    float2 v = ((const float2*)nf_in)[idx];
    *(float2*)(out + OUT_NF + (size_t)i * 130 + k * 2) = v;
}

extern "C" void kernel_launch(void* const* d_in, const int* in_sizes, int n_in,
                              void* d_out, int out_size, void* d_ws, size_t ws_size,
                              hipStream_t stream) {
    const float* node_attrs = (const float*)d_in[1];
    const int* edge_index = (const int*)d_in[2];
    const float* edge_length = (const float*)d_in[3];
    const float* kappa = (const float*)d_in[4];
    const float* node_feats = (const float*)d_in[5];
    const float* ref_eta = (const float*)d_in[6];
    const float* ref_log_sigma = (const float*)d_in[7];
    const float* ref_A = (const float*)d_in[8];
    const float* ref_B = (const float*)d_in[9];
    const float* ref_C = (const float*)d_in[10];
    const float* ref_D = (const float*)d_in[11];
    const float* ref_mu = (const float*)d_in[12];
    const float* short_energy = (const float*)d_in[13];
    const float* atomic_short = (const float*)d_in[14];

    float* out = (float*)d_out;
    char* ws = (char*)d_ws;
    int* winner = (int*)ws;                       // TT*64 ints = 1 MiB
    float* P_in = (float*)(ws + (1 << 20));
    float* W_in = P_in + TT;
    float* aE2b = W_in + TT;
    float* qc = aE2b + TT;
    float* coef = qc + TT;
    float* qsum = coef + TT;

    hipMemsetAsync(winner, 0xFF, (size_t)TT * 64 * sizeof(int), stream);
    k_scatter<<<EDGES / 256, 256, 0, stream>>>(edge_index, winner);
    k_graph<<<G, 256, 0, stream>>>(node_attrs, edge_length, kappa, ref_eta,
                                   ref_log_sigma, ref_A, ref_B, ref_C, ref_D,
                                   ref_mu, winner, P_in, W_in, aE2b, qc, coef,
                                   qsum);
    k_feats<<<(TT * 64) / 256, 256, 0, stream>>>(node_feats, out);
    k_node<<<TT / 256, 256, 0, stream>>>(P_in, W_in, aE2b, qc, coef, qsum,
                                         atomic_short, short_energy, out);
}

// Round 3
// 40.587 us; speedup vs baseline: 1.4038x; 1.0354x over previous
//
#include <hip/hip_runtime.h>

#define G 64
#define NN 64
#define TT 4096
#define EDGES 131072
#define FF 128

#define OUT_ETOT 0
#define OUT_NODEE 64
#define OUT_Q (64 + 4096)
#define OUT_NF (64 + 4096 + 4096)

__device__ __forceinline__ float wave_sum_f(float v) {
#pragma unroll
    for (int m = 1; m < 64; m <<= 1) v += __shfl_xor(v, m);
    return v;
}
__device__ __forceinline__ double wave_sum_d(double v) {
#pragma unroll
    for (int m = 1; m < 64; m <<= 1) v += __shfl_xor(v, m);
    return v;
}
// uniform-index broadcast via readlane (SALU, off the ds_permute path)
__device__ __forceinline__ double bcast_d(double v, int j) {
    union { double d; int i[2]; } u;
    u.d = v;
    int lo = __builtin_amdgcn_readlane(u.i[0], j);
    int hi = __builtin_amdgcn_readlane(u.i[1], j);
    union { int i[2]; double d; } r;
    r.i[0] = lo; r.i[1] = hi;
    return r.d;
}

// ---------------- edge scatter: last-write-wins via atomicMax on edge index ----
__global__ void k_scatter(const int* __restrict__ ei, int* __restrict__ winner) {
    int e = blockIdx.x * blockDim.x + threadIdx.x;
    if (e >= EDGES) return;
    int i = ei[e];
    int j = ei[EDGES + e];
    atomicMax(&winner[(i << 6) + (j & 63)], e);
}

// ---------------- per-graph kernel: matrices, E2b, triangular solve, matvecs ---
__global__ __launch_bounds__(256, 1) void k_graph(
    const float* __restrict__ node_attrs, const float* __restrict__ edge_len,
    const float* __restrict__ kappa, const float* __restrict__ ref_eta,
    const float* __restrict__ ref_log_sigma, const float* __restrict__ ref_A,
    const float* __restrict__ ref_B, const float* __restrict__ ref_C,
    const float* __restrict__ ref_D, const float* __restrict__ ref_mu,
    const int* __restrict__ winner,
    float* __restrict__ P_in, float* __restrict__ W_in, float* __restrict__ aE2b,
    float* __restrict__ qc, float* __restrict__ coef, float* __restrict__ qsum) {
    __shared__ float s_factor[64][65];
    __shared__ float s_fcf[64][65];
    __shared__ float s_q[64];
    __shared__ int s_type[64];
    __shared__ float s_gam[4][4];
    __shared__ float s_diag[64];
    __shared__ float s_sigma[4];
    __shared__ float s_A[16], s_B[16], s_C[16], s_D[16], s_mu[16];

    const int g = blockIdx.x;
    const int tid = threadIdx.x;
    const int lane = tid & 63;
    const int wv = tid >> 6;
    const float SQRT_PI = 1.7724538509055159f;
    const float SQRT2 = 1.41421356237309515f;
    const float th1 = tanhf(1.0f);
    const float c1 = th1 * th1 * th1;

    // ---- batch ALL global loads for phase 1 up-front (32 independent loads) --
    int widx[16];
#pragma unroll
    for (int r = 0; r < 16; ++r) {
        int li = (r << 2) + wv;
        widx[r] = winner[(((g << 6) + li) << 6) + lane];
    }
    float Rv[16];
#pragma unroll
    for (int r = 0; r < 16; ++r) {
        Rv[r] = (widx[r] >= 0) ? edge_len[widx[r]] : 0.5f;
    }

    if (tid < 4) s_sigma[tid] = __expf(ref_log_sigma[tid]);
    if (tid < 16) {
        s_A[tid] = ref_A[tid]; s_B[tid] = ref_B[tid]; s_C[tid] = ref_C[tid];
        s_D[tid] = ref_D[tid]; s_mu[tid] = ref_mu[tid];
    }
    if (tid < 64) {
        const float* row = node_attrs + (size_t)(g * 64 + tid) * 4;
        int t = 0;
        float best = row[0];
#pragma unroll
        for (int k = 1; k < 4; ++k) {
            float v = row[k];
            if (v > best) { best = v; t = k; }
        }
        s_type[tid] = t;
        float sg = __expf(ref_log_sigma[t]);
        s_diag[tid] = ref_eta[t] + 1.0f / (sg * SQRT_PI);
        coef[g * 64 + tid] = 0.5f / (sg * SQRT_PI);
    }
    __syncthreads();
    if (tid < 16) {
        int a = tid >> 2, b = tid & 3;
        s_gam[a][b] = sqrtf(s_sigma[a] * s_sigma[a] + s_sigma[b] * s_sigma[b]);
    }
    __syncthreads();

    // ---- phase 1: build factor / factor*Fc matrices; E2b row sums (unrolled) -
    const int tj = s_type[lane];
    float e2b[16];
#pragma unroll
    for (int r = 0; r < 16; ++r) {
        int li = (r << 2) + wv;
        float R = Rv[r];
        int ti = s_type[li];
        float gam = s_gam[ti][tj];
        float rinv = __frcp_rn(R);
        float factor = erff(R / (SQRT2 * gam)) * rinv;
        float fc;
        if (R < 1.0f) fc = c1;
        else if (R <= 6.0f) {
            float x = 1.0f - (R - 1.0f) * 0.2f;      // in [0,1]
            float ex = __expf(2.0f * x);
            float t = (ex - 1.0f) / (ex + 1.0f);     // tanh(x)
            fc = t * t * t;
        } else fc = 0.0f;
        s_factor[li][lane] = factor;
        s_fcf[li][lane] = factor * fc;
        float e = 0.0f;
        if (li != lane) {
            int t4 = ti * 4 + tj;
            float r2 = rinv * rinv;
            float r6 = r2 * r2 * r2;
            e = (s_A[t4] * __expf(s_B[t4] * (s_mu[t4] - R)) - s_C[t4] * r6 -
                 s_D[t4] * (r6 * r2)) * fc;
        }
        e2b[r] = e;
    }
    // 16 independent butterfly chains, interleaved for ILP
#pragma unroll
    for (int m = 1; m < 64; m <<= 1) {
#pragma unroll
        for (int r = 0; r < 16; ++r) e2b[r] += __shfl_xor(e2b[r], m);
    }
    if (lane == 0) {
#pragma unroll
        for (int r = 0; r < 16; ++r)
            aE2b[(g << 6) + (r << 2) + wv] = 0.5f * e2b[r];
    }
    __syncthreads();

    // ---- phase 2: dual forward substitution (fp64), one wave ----------------
    // broadcast via readlane (uniform j) instead of ds_bpermute shfl
    if (tid < 64) {
        const int i = tid;
        double Ld = (double)(s_diag[i] + s_factor[i][i]);
        double inv = 1.0 / Ld;
        double au = 1.0;
        double av = (double)kappa[g * 64 + i];
        double my_u = 0.0, my_v = 0.0;
        for (int j = 0; j < 64; ++j) {
            double ij = bcast_d(inv, j);
            double uj = bcast_d(au, j) * ij;
            double vj = bcast_d(av, j) * ij;
            if (i == j) { my_u = uj; my_v = vj; }
            if (i > j) {
                double Lij = (double)s_factor[i][j];
                au -= Lij * uj;
                av -= Lij * vj;
            }
        }
        double Su = wave_sum_d(my_u);
        double Sv = wave_sum_d(my_v);
        double lam = Sv / Su;  // q = -v + (Sv/Su)*u  (ensures sum(q)=0)
        float q = (float)(-my_v + lam * my_u);
        s_q[i] = q;
        qc[g * 64 + i] = q;
        float sq = wave_sum_f(q);
        if (i == 0) qsum[g] = sq;
    }
    __syncthreads();

    // ---- phase 3: within-block matvec row sums (unrolled, interleaved) -------
    const float qlane = s_q[lane];
    float p[16], w[16];
#pragma unroll
    for (int r = 0; r < 16; ++r) {
        int li = (r << 2) + wv;
        p[r] = s_fcf[li][lane] * qlane;
        w[r] = s_factor[li][lane] * qlane;
    }
#pragma unroll
    for (int m = 1; m < 64; m <<= 1) {
#pragma unroll
        for (int r = 0; r < 16; ++r) {
            p[r] += __shfl_xor(p[r], m);
            w[r] += __shfl_xor(w[r], m);
        }
    }
    if (lane == 0) {
#pragma unroll
        for (int r = 0; r < 16; ++r) {
            P_in[(g << 6) + (r << 2) + wv] = p[r];
            W_in[(g << 6) + (r << 2) + wv] = w[r];
        }
    }
}

// ---------------- per-node epilogue (fused Qall + E_tot reduction) ------------
__global__ __launch_bounds__(256) void k_node(
    const float* __restrict__ P_in, const float* __restrict__ W_in,
    const float* __restrict__ aE2b, const float* __restrict__ qc,
    const float* __restrict__ coef, const float* __restrict__ qsum,
    const float* __restrict__ atomic_short, const float* __restrict__ short_e,
    float* __restrict__ out) {
    int i = blockIdx.x * blockDim.x + threadIdx.x;  // node id; wave == graph
    int lane = threadIdx.x & 63;
    int g = i >> 6;
    const float th1 = tanhf(1.0f);
    const float c1 = th1 * th1 * th1;
    const float factor_off = erff(0.5f / (1.41421356237309515f * 0.5f)) / 0.5f;

    float Qall = wave_sum_f(qsum[lane]);
    float off = Qall - qsum[g];
    float q = qc[i];
    float ap = P_in[i] + factor_off * c1 * off;
    float V = W_in[i] + factor_off * off + coef[i] * q;
    float aEel = q * V;
    float e2 = aE2b[i];
    out[OUT_NODEE + i] = aEel + e2 + atomic_short[i];
    out[OUT_Q + i] = q;
    float* nf = out + OUT_NF + (size_t)i * 130;
    nf[128] = q;
    nf[129] = ap;
    float etot = wave_sum_f(aEel + e2);
    if (lane == 0) out[OUT_ETOT + g] = etot + short_e[g];
}

// ---------------- node_feats copy (float2, stride-130 rows) -------------------
__global__ __launch_bounds__(256) void k_feats(const float* __restrict__ nf_in,
                                               float* __restrict__ out) {
    int idx = blockIdx.x * blockDim.x + threadIdx.x;  // TT*64 float2 units
    if (idx >= TT * 64) return;
    int i = idx >> 6;
    int k = idx & 63;
    float2 v = ((const float2*)nf_in)[idx];
    *(float2*)(out + OUT_NF + (size_t)i * 130 + k * 2) = v;
}

extern "C" void kernel_launch(void* const* d_in, const int* in_sizes, int n_in,
                              void* d_out, int out_size, void* d_ws, size_t ws_size,
                              hipStream_t stream) {
    const float* node_attrs = (const float*)d_in[1];
    const int* edge_index = (const int*)d_in[2];
    const float* edge_length = (const float*)d_in[3];
    const float* kappa = (const float*)d_in[4];
    const float* node_feats = (const float*)d_in[5];
    const float* ref_eta = (const float*)d_in[6];
    const float* ref_log_sigma = (const float*)d_in[7];
    const float* ref_A = (const float*)d_in[8];
    const float* ref_B = (const float*)d_in[9];
    const float* ref_C = (const float*)d_in[10];
    const float* ref_D = (const float*)d_in[11];
    const float* ref_mu = (const float*)d_in[12];
    const float* short_energy = (const float*)d_in[13];
    const float* atomic_short = (const float*)d_in[14];

    float* out = (float*)d_out;
    char* ws = (char*)d_ws;
    int* winner = (int*)ws;                       // TT*64 ints = 1 MiB
    float* P_in = (float*)(ws + (1 << 20));
    float* W_in = P_in + TT;
    float* aE2b = W_in + TT;
    float* qc = aE2b + TT;
    float* coef = qc + TT;
    float* qsum = coef + TT;

    hipMemsetAsync(winner, 0xFF, (size_t)TT * 64 * sizeof(int), stream);
    k_scatter<<<EDGES / 256, 256, 0, stream>>>(edge_index, winner);
    k_graph<<<G, 256, 0, stream>>>(node_attrs, edge_length, kappa, ref_eta,
                                   ref_log_sigma, ref_A, ref_B, ref_C, ref_D,
                                   ref_mu, winner, P_in, W_in, aE2b, qc, coef,
                                   qsum);
    k_feats<<<(TT * 64) / 256, 256, 0, stream>>>(node_feats, out);
    k_node<<<TT / 256, 256, 0, stream>>>(P_in, W_in, aE2b, qc, coef, qsum,
                                         atomic_short, short_energy, out);
}

// Round 4
// 33.821 us; speedup vs baseline: 1.6846x; 1.2000x over previous
//
#include <hip/hip_runtime.h>

#define G 64
#define NN 64
#define TT 4096
#define EDGES 131072

#define OUT_ETOT 0
#define OUT_NODEE 64
#define OUT_Q (64 + 4096)
#define OUT_NF (64 + 4096 + 4096)

__device__ __forceinline__ float wave_sum_f(float v) {
#pragma unroll
    for (int m = 1; m < 64; m <<= 1) v += __shfl_xor(v, m);
    return v;
}
__device__ __forceinline__ double wave_sum_d(double v) {
#pragma unroll
    for (int m = 1; m < 64; m <<= 1) v += __shfl_xor(v, m);
    return v;
}
__device__ __forceinline__ double bcast_d(double v, int j) {
    union { double d; int i[2]; } u;
    u.d = v;
    union { int i[2]; double d; } r;
    r.i[0] = __builtin_amdgcn_readlane(u.i[0], j);
    r.i[1] = __builtin_amdgcn_readlane(u.i[1], j);
    return r.d;
}
__device__ __forceinline__ int type_of(float4 na) {
    int t = 0;
    float best = na.x;
    if (na.y > best) { best = na.y; t = 1; }
    if (na.z > best) { best = na.z; t = 2; }
    if (na.w > best) { best = na.w; t = 3; }
    return t;
}

// ---------------- edge scatter: last-write-wins via atomicMax on edge index ----
__global__ void k_scatter(const int* __restrict__ ei, int* __restrict__ winner) {
    int e = blockIdx.x * blockDim.x + threadIdx.x;
    if (e >= EDGES) return;
    int i = ei[e];
    int j = ei[EDGES + e];
    atomicMax(&winner[(i << 6) + (j & 63)], e);
}

// ---------------- k_build: wave = matrix row, lane = column --------------------
// Writes factor, factor*Fc (1 MiB each) and per-row E2b sums. Full-chip TLP.
__global__ __launch_bounds__(256) void k_build(
    const float* __restrict__ node_attrs, const float* __restrict__ edge_len,
    const int* __restrict__ winner, const float* __restrict__ ref_log_sigma,
    const float* __restrict__ ref_A, const float* __restrict__ ref_B,
    const float* __restrict__ ref_C, const float* __restrict__ ref_D,
    const float* __restrict__ ref_mu,
    float* __restrict__ factor_g, float* __restrict__ fcf_g,
    float* __restrict__ aE2b) {
    const int row = blockIdx.x * 4 + (threadIdx.x >> 6);  // 0..4095 (node i)
    const int lane = threadIdx.x & 63;                    // column j
    const int g = row >> 6;
    const int ir = row & 63;
    const float th1 = tanhf(1.0f);
    const float c1 = th1 * th1 * th1;

    // issue independent loads up front
    const int wdx = winner[(row << 6) + lane];
    const float4 na = *(const float4*)(node_attrs + ((size_t)((g << 6) + lane) << 2));

    const float R = (wdx >= 0) ? edge_len[wdx] : 0.5f;
    const int tj = type_of(na);
    const int ti = __shfl(tj, ir);
    const float sgj = __expf(ref_log_sigma[tj]);
    const float sgi = __shfl(sgj, ir);
    const float gam = sqrtf(sgi * sgi + sgj * sgj);

    const float rinv = __frcp_rn(R);
    const float factor = erff(R * (0.70710678118654752f / gam)) * rinv;
    float fc;
    if (R < 1.0f) fc = c1;
    else if (R <= 6.0f) {
        float x = 1.0f - (R - 1.0f) * 0.2f;  // in [0,1]
        float ex = __expf(2.0f * x);
        float t = (ex - 1.0f) / (ex + 1.0f);  // tanh(x)
        fc = t * t * t;
    } else fc = 0.0f;

    factor_g[(row << 6) + lane] = factor;
    fcf_g[(row << 6) + lane] = factor * fc;

    float e = 0.0f;
    if (ir != lane) {
        int t4 = ti * 4 + tj;
        float r2 = rinv * rinv;
        float r6 = r2 * r2 * r2;
        e = (ref_A[t4] * __expf(ref_B[t4] * (ref_mu[t4] - R)) - ref_C[t4] * r6 -
             ref_D[t4] * (r6 * r2)) * fc;
    }
    e = wave_sum_f(e);
    if (lane == 0) aE2b[row] = 0.5f * e;
}

// ---------------- k_solve: per-graph fp64 dual forward substitution -----------
__global__ __launch_bounds__(256) void k_solve(
    const float* __restrict__ factor_g, const float* __restrict__ node_attrs,
    const float* __restrict__ kappa, const float* __restrict__ ref_eta,
    const float* __restrict__ ref_log_sigma,
    float* __restrict__ qc, float* __restrict__ qsum) {
    __shared__ float sL[64][65];
    __shared__ float s_diag[64];
    const int g = blockIdx.x;
    const int tid = threadIdx.x;
    const float SQRT_PI = 1.7724538509055159f;

    // stage 16 KB factor block into LDS, coalesced float4
    const float4* src4 = (const float4*)(factor_g + ((size_t)g << 12));
#pragma unroll
    for (int k = 0; k < 4; ++k) {
        int f = k * 256 + tid;          // float4 index 0..1023
        float4 v = src4[f];
        int rr = f >> 4, cc = (f & 15) << 2;
        sL[rr][cc] = v.x; sL[rr][cc + 1] = v.y;
        sL[rr][cc + 2] = v.z; sL[rr][cc + 3] = v.w;
    }
    if (tid < 64) {
        float4 na = *(const float4*)(node_attrs + ((size_t)((g << 6) + tid) << 2));
        int t = type_of(na);
        float sg = __expf(ref_log_sigma[t]);
        s_diag[tid] = ref_eta[t] + 1.0f / (sg * SQRT_PI);
    }
    __syncthreads();

    if (tid < 64) {
        const int i = tid;
        double Ld = (double)(s_diag[i] + sL[i][i]);
        double inv = 1.0 / Ld;
        double au = 1.0;
        double av = (double)kappa[(g << 6) + i];
        double my_u = 0.0, my_v = 0.0;
        for (int j = 0; j < 64; ++j) {
            double ij = bcast_d(inv, j);
            double uj = bcast_d(au, j) * ij;
            double vj = bcast_d(av, j) * ij;
            if (i == j) { my_u = uj; my_v = vj; }
            if (i > j) {
                double Lij = (double)sL[i][j];
                au -= Lij * uj;
                av -= Lij * vj;
            }
        }
        double Su = wave_sum_d(my_u);
        double Sv = wave_sum_d(my_v);
        double lam = Sv / Su;  // q = -v + (Sv/Su)*u  (ensures sum(q)=0)
        float q = (float)(-my_v + lam * my_u);
        qc[(g << 6) + i] = q;
        float sq = wave_sum_f(q);
        if (i == 0) qsum[g] = sq;
    }
}

// ---------------- k_final: wave = node; matvec + epilogue + feats copy --------
__global__ __launch_bounds__(256) void k_final(
    const float* __restrict__ factor_g, const float* __restrict__ fcf_g,
    const float* __restrict__ qc, const float* __restrict__ qsum,
    const float* __restrict__ aE2b, const float* __restrict__ node_attrs,
    const float* __restrict__ ref_log_sigma,
    const float* __restrict__ atomic_short, const float* __restrict__ nf_in,
    float* __restrict__ aEel_ws, float* __restrict__ out) {
    const int i = blockIdx.x * 4 + (threadIdx.x >> 6);  // node id
    const int lane = threadIdx.x & 63;
    const int g = i >> 6;
    const float SQRT_PI = 1.7724538509055159f;
    const float th1 = tanhf(1.0f);
    const float c1 = th1 * th1 * th1;
    const float factor_off = erff(0.70710678118654752f / 0.5f) * 2.0f;  // erf(R/(√2·EPS))/R at R=EPS

    // independent loads
    const float qj = qc[(g << 6) + lane];
    const float f = factor_g[(i << 6) + lane];
    const float fcf = fcf_g[(i << 6) + lane];
    const float qs = qsum[lane];
    const float2 v2 = ((const float2*)nf_in)[(i << 6) + lane];
    const float4 na = *(const float4*)(node_attrs + ((size_t)i << 2));

    float p = fcf * qj;
    float w = f * qj;
#pragma unroll
    for (int m = 1; m < 64; m <<= 1) {
        p += __shfl_xor(p, m);
        w += __shfl_xor(w, m);
    }
    float Qall = wave_sum_f(qs);

    // feats copy: 2 floats/lane into stride-130 rows
    *(float2*)(out + OUT_NF + (size_t)i * 130 + lane * 2) = v2;

    if (lane == 0) {
        float off = Qall - qsum[g];
        int t = type_of(na);
        float sg = __expf(ref_log_sigma[t]);
        float coef = 0.5f / (sg * SQRT_PI);
        float q = qc[i];
        float ap = p + factor_off * c1 * off;
        float V = w + factor_off * off + coef * q;
        float aEel = q * V;
        aEel_ws[i] = aEel;
        out[OUT_NODEE + i] = aEel + aE2b[i] + atomic_short[i];
        out[OUT_Q + i] = q;
        out[OUT_NF + (size_t)i * 130 + 128] = q;
        out[OUT_NF + (size_t)i * 130 + 129] = ap;
    }
}

// ---------------- per-graph energy total --------------------------------------
__global__ void k_etot(const float* __restrict__ aEel,
                       const float* __restrict__ aE2b,
                       const float* __restrict__ short_e,
                       float* __restrict__ out) {
    int g = blockIdx.x;
    int lane = threadIdx.x;
    float v = aEel[(g << 6) + lane] + aE2b[(g << 6) + lane];
    v = wave_sum_f(v);
    if (lane == 0) out[OUT_ETOT + g] = v + short_e[g];
}

extern "C" void kernel_launch(void* const* d_in, const int* in_sizes, int n_in,
                              void* d_out, int out_size, void* d_ws, size_t ws_size,
                              hipStream_t stream) {
    const float* node_attrs = (const float*)d_in[1];
    const int* edge_index = (const int*)d_in[2];
    const float* edge_length = (const float*)d_in[3];
    const float* kappa = (const float*)d_in[4];
    const float* node_feats = (const float*)d_in[5];
    const float* ref_eta = (const float*)d_in[6];
    const float* ref_log_sigma = (const float*)d_in[7];
    const float* ref_A = (const float*)d_in[8];
    const float* ref_B = (const float*)d_in[9];
    const float* ref_C = (const float*)d_in[10];
    const float* ref_D = (const float*)d_in[11];
    const float* ref_mu = (const float*)d_in[12];
    const float* short_energy = (const float*)d_in[13];
    const float* atomic_short = (const float*)d_in[14];

    float* out = (float*)d_out;
    char* ws = (char*)d_ws;
    int* winner = (int*)ws;                          // 1 MiB
    float* factor_g = (float*)(ws + (1 << 20));      // 1 MiB
    float* fcf_g = factor_g + TT * 64;               // 1 MiB
    float* aE2b = fcf_g + TT * 64;
    float* qc = aE2b + TT;
    float* qsum = qc + TT;
    float* aEel = qsum + G;

    hipMemsetAsync(winner, 0xFF, (size_t)TT * 64 * sizeof(int), stream);
    k_scatter<<<EDGES / 256, 256, 0, stream>>>(edge_index, winner);
    k_build<<<TT / 4, 256, 0, stream>>>(node_attrs, edge_length, winner,
                                        ref_log_sigma, ref_A, ref_B, ref_C,
                                        ref_D, ref_mu, factor_g, fcf_g, aE2b);
    k_solve<<<G, 256, 0, stream>>>(factor_g, node_attrs, kappa, ref_eta,
                                   ref_log_sigma, qc, qsum);
    k_final<<<TT / 4, 256, 0, stream>>>(factor_g, fcf_g, qc, qsum, aE2b,
                                        node_attrs, ref_log_sigma, atomic_short,
                                        node_feats, aEel, out);
    k_etot<<<G, 64, 0, stream>>>(aEel, aE2b, short_energy, out);
}